// Round 3
// baseline (124.973 us; speedup 1.0000x reference)
//
#include <hip/hip_runtime.h>
#include <cstdint>

#define DD 24
#define AA 13824          // 24*24*24
#define NF4 3456          // AA/4
#define BLOCK 1024
#define TOPK 60
#define NMS_TOPK 20
#define THRESH 0.15f
#define NMS_THR 0.05f
#define BUFCAP 8192

__global__ __launch_bounds__(BLOCK, 1) void detpost(
    const float* __restrict__ cls,
    const float* __restrict__ shp,
    const float* __restrict__ off,
    float* __restrict__ out)
{
    __shared__ float    s_bufv[BUFCAP];
    __shared__ int      s_bufi[BUFCAP];
    __shared__ float    s_topv[TOPK];
    __shared__ int      s_topi[TOPK];
    __shared__ float    s_lo[3][TOPK], s_hi[3][TOPK], s_vol[TOPK];
    __shared__ float    s_det[TOPK][8];      // 1, score, cz, cy, cx, ez, ey, ex
    __shared__ unsigned s_mLo[TOPK], s_mHi[TOPK];
    __shared__ int      s_cnt2, s_cnt1, s_cnt0, s_cnt;
    __shared__ float    s_thr;
    __shared__ unsigned long long s_candmask, s_keptmask;

    const int b   = blockIdx.x;
    const int tid = threadIdx.x;

    if (tid < TOPK) { s_mLo[tid] = 0u; s_mHi[tid] = 0u; }
    if (tid == 0) { s_cnt2 = 0; s_cnt1 = 0; s_cnt0 = 0; s_cnt = 0; }
    __syncthreads();

    // ---- Load cls into registers (fully coalesced float4) ----
    const float4* cls4 = (const float4*)(cls + (size_t)b * AA);
    const bool has3 = (tid + 3072) < NF4;    // NF4 = 3456: threads 0..383
    float4 r0 = cls4[tid];
    float4 r1 = cls4[tid + 1024];
    float4 r2 = cls4[tid + 2048];
    float4 r3 = has3 ? cls4[tid + 3072] : make_float4(-1e30f, -1e30f, -1e30f, -1e30f);

    // ---- Tier counts: how many values exceed 2.0 / 1.0 / 0.0 ----
    int c2 = 0, c1 = 0, c0 = 0;
    #define CNT(v) { c2 += (v) > 2.0f; c1 += (v) > 1.0f; c0 += (v) > 0.0f; }
    CNT(r0.x) CNT(r0.y) CNT(r0.z) CNT(r0.w)
    CNT(r1.x) CNT(r1.y) CNT(r1.z) CNT(r1.w)
    CNT(r2.x) CNT(r2.y) CNT(r2.z) CNT(r2.w)
    CNT(r3.x) CNT(r3.y) CNT(r3.z) CNT(r3.w)
    #undef CNT
    // pack (each per-thread count <= 16; wave sum <= 1024 fits in 10 bits)
    int p = c2 | (c1 << 10) | (c0 << 20);
    #pragma unroll
    for (int d2 = 32; d2 >= 1; d2 >>= 1) p += __shfl_down(p, d2, 64);
    if ((tid & 63) == 0) {
        atomicAdd(&s_cnt2, p & 1023);
        atomicAdd(&s_cnt1, (p >> 10) & 1023);
        atomicAdd(&s_cnt0, (p >> 20) & 1023);
    }
    __syncthreads();
    if (tid == 0) {
        s_thr = (s_cnt2 >= TOPK) ? 2.0f
              : (s_cnt1 >= TOPK) ? 1.0f
              : (s_cnt0 >= TOPK) ? 0.0f : -1e30f;
    }
    __syncthreads();
    const float thr = s_thr;

    // ---- Collect candidates (> thr) from registers ----
    {
        const int b0 = 4 * tid, b1 = 4 * (tid + 1024), b2 = 4 * (tid + 2048), b3 = 4 * (tid + 3072);
        #define COLL(v, e) if ((v) > thr) { \
            int pos = atomicAdd(&s_cnt, 1); \
            if (pos < BUFCAP) { s_bufv[pos] = (v); s_bufi[pos] = (e); } }
        COLL(r0.x, b0 + 0) COLL(r0.y, b0 + 1) COLL(r0.z, b0 + 2) COLL(r0.w, b0 + 3)
        COLL(r1.x, b1 + 0) COLL(r1.y, b1 + 1) COLL(r1.z, b1 + 2) COLL(r1.w, b1 + 3)
        COLL(r2.x, b2 + 0) COLL(r2.y, b2 + 1) COLL(r2.z, b2 + 2) COLL(r2.w, b2 + 3)
        if (has3) { COLL(r3.x, b3 + 0) COLL(r3.y, b3 + 1) COLL(r3.z, b3 + 2) COLL(r3.w, b3 + 3) }
        #undef COLL
    }
    __syncthreads();
    int C = s_cnt; if (C > BUFCAP) C = BUFCAP;

    // ---- Exact top-60 by rank counting (desc value, tie: lower index first) ----
    for (int j = tid; j < C; j += BLOCK) {
        const float vj = s_bufv[j];
        const int   ij = s_bufi[j];
        int r = 0;
        for (int k = 0; k < C; ++k) {
            const float vk = s_bufv[k];
            const int   ik = s_bufi[k];
            r += (int)((vk > vj) || (vk == vj && ik < ij));
        }
        if (r < TOPK) { s_topv[r] = vj; s_topi[r] = ij; }
    }
    __syncthreads();

    // ---- Decode boxes for the 60 finalists ----
    if (tid < TOPK) {
        const float v = s_topv[tid];
        const int   a = s_topi[tid];
        const float score = 1.0f / (1.0f + expf(-v));
        const int z  = a / (DD * DD);
        const int y  = (a / DD) % DD;
        const int xg = a % DD;
        const size_t base3 = (size_t)b * 3 * AA;
        const float o0 = off[base3 + 0 * AA + a];
        const float o1 = off[base3 + 1 * AA + a];
        const float o2 = off[base3 + 2 * AA + a];
        const float s0 = shp[base3 + 0 * AA + a];
        const float s1 = shp[base3 + 1 * AA + a];
        const float s2 = shp[base3 + 2 * AA + a];
        const float cz = ((float)z  + o0) * 4.0f;
        const float cy = ((float)y  + o1) * 4.0f;
        const float cx = ((float)xg + o2) * 4.0f;
        const float ez = 2.0f * s0, ey = 2.0f * s1, ex = 2.0f * s2;
        // mirror reference fp op order exactly
        s_lo[0][tid] = cz - ez * 0.5f;  s_hi[0][tid] = cz + ez * 0.5f;
        s_lo[1][tid] = cy - ey * 0.5f;  s_hi[1][tid] = cy + ey * 0.5f;
        s_lo[2][tid] = cx - ex * 0.5f;  s_hi[2][tid] = cx + ex * 0.5f;
        s_vol[tid]   = (ez * ey) * ex;
        s_det[tid][0] = 1.0f;  s_det[tid][1] = score;
        s_det[tid][2] = cz;    s_det[tid][3] = cy;   s_det[tid][4] = cx;
        s_det[tid][5] = ez;    s_det[tid][6] = ey;   s_det[tid][7] = ex;
    }
    __syncthreads();

    // ---- Candidate mask (thread 0) + parallel IoU suppression masks ----
    if (tid == 0) {
        unsigned long long cm = 0ull; int nv = 0;
        for (int i = 0; i < TOPK; ++i) {
            if (s_det[i][1] > THRESH) {
                if (nv < NMS_TOPK) cm |= (1ull << i);
                ++nv;
            }
        }
        s_candmask = cm;
    }
    for (int pr = tid; pr < TOPK * TOPK; pr += BLOCK) {
        const int i = pr / TOPK, j = pr - i * TOPK;
        if (i != j) {
            const float tz = fmaxf(fminf(s_hi[0][i], s_hi[0][j]) - fmaxf(s_lo[0][i], s_lo[0][j]), 0.0f);
            const float ty = fmaxf(fminf(s_hi[1][i], s_hi[1][j]) - fmaxf(s_lo[1][i], s_lo[1][j]), 0.0f);
            const float tx = fmaxf(fminf(s_hi[2][i], s_hi[2][j]) - fmaxf(s_lo[2][i], s_lo[2][j]), 0.0f);
            const float inter = (tz * ty) * tx;
            const float uni = (s_vol[i] + s_vol[j]) - inter;
            const float iou = inter / fmaxf(uni, 1e-8f);
            if (iou > NMS_THR) {
                if (j < 32) atomicOr(&s_mLo[i], 1u << j);
                else        atomicOr(&s_mHi[i], 1u << (j - 32));
            }
        }
    }
    __syncthreads();

    // ---- Serial greedy NMS (pure bit ops, thread 0) ----
    if (tid == 0) {
        unsigned long long supp = 0ull, kept = 0ull;
        const unsigned long long cm = s_candmask;
        for (int i = 0; i < TOPK; ++i) {
            const unsigned long long bit = 1ull << i;
            if ((cm & bit) && !(supp & bit)) {
                kept |= bit;
                supp |= ((unsigned long long)s_mHi[i] << 32) | s_mLo[i];
            }
        }
        s_keptmask = kept;
    }
    __syncthreads();

    // ---- Output ----
    const unsigned long long kept = s_keptmask;
    const int K = __popcll(kept);
    float* ob = out + (size_t)b * (TOPK * 8);
    if (tid < TOPK && ((kept >> tid) & 1ull)) {
        const int r = __popcll(kept & ((1ull << tid) - 1ull));
        float* row = ob + r * 8;
        #pragma unroll
        for (int q = 0; q < 8; ++q) row[q] = s_det[tid][q];
    }
    const int fill = (TOPK - K) * 8;
    for (int idx = tid; idx < fill; idx += BLOCK) ob[K * 8 + idx] = -1.0f;
}

extern "C" void kernel_launch(void* const* d_in, const int* in_sizes, int n_in,
                              void* d_out, int out_size, void* d_ws, size_t ws_size,
                              hipStream_t stream) {
    (void)n_in; (void)out_size; (void)d_ws; (void)ws_size;
    const float* cls = (const float*)d_in[0];
    const float* shp = (const float*)d_in[1];
    const float* off = (const float*)d_in[2];
    float* out = (float*)d_out;
    const int B = in_sizes[0] / AA;   // 256
    detpost<<<B, BLOCK, 0, stream>>>(cls, shp, off, out);
}